// Round 5
// baseline (27.008 us; speedup 1.0000x reference)
//
#include <hip/hip_runtime.h>

// ---------------------------------------------------------------------------
// FFT_Conv_Layer == 3x3 "same" spatial conv with flipped REAL filter plane:
//   out[b,o,y,x] = sum_{i,ky,kx} filts[0,i,o,ky,kx,0] * img[b,i,y+1-ky,x+1-kx]
// (imag filter plane only reaches the imaginary output, dropped by .real;
//  circular conv at S=66 == full linear conv; crop [1:-1] => "same" conv.)
//
// R2: wave tile 64x32 made the kernel LDS-issue-bound (0.5 ds_read_b128 per
// MFMA -> 6.9k cyc/CU vs 5.6k MFMA floor) with only 2 blocks/CU of overlap.
// R3: wave tile 64x64 (4x4 frags), 128-thr blocks (wave = 1 output row),
// 4 blocks/CU, XCD-swizzled bids so each XCD's staging re-reads hit its L2.
// (R3/R4 benches lost to an unresponsive container; resubmitted unchanged.)
// ---------------------------------------------------------------------------

typedef _Float16 f16x8 __attribute__((ext_vector_type(8)));
typedef float    f32x4 __attribute__((ext_vector_type(4)));

#define NB 16
#define NC 64
#define NH 64
#define NW 64
#define CHUNKS 528                 // 66 xp positions * 8 channel-chunks per slab
#define SLAB_BYTES (CHUNKS * 16)   // 8448 B per image row slab
#define WF_HALFS (9 * 2 * 4 * 64 * 8)  // taps * kc * n * lane * elem = 36864

// ---------------------------------------------------------------------------
// prep_w: filts [1][inC][outC][3][3][2] f32 -> per-fragment f16 weights
//   Wf[t][kc][n][lane][e] = filts[0][ i=kc*32+(l/16)*8+e ][ o=n*16+l%16 ][ky][kx][0]
// Same (lane-group,e)->k labeling as the A fragments, so the MFMA k-pairing
// is consistent regardless of the hardware's internal k bijection.
// ---------------------------------------------------------------------------
__global__ __launch_bounds__(256) void prep_w(const float* __restrict__ filts,
                                              _Float16* __restrict__ wf) {
    const int f = blockIdx.x * 256 + threadIdx.x;
    if (f >= WF_HALFS) return;
    const int e  = f & 7;
    const int l  = (f >> 3) & 63;
    const int n  = (f >> 9) & 3;
    const int kc = (f >> 11) & 1;
    const int t  = f >> 12;              // 0..8
    const int i  = kc * 32 + (l >> 4) * 8 + e;
    const int o  = n * 16 + (l & 15);
    const int ky = t / 3, kx = t % 3;
    wf[f] = (_Float16)filts[(((i * 64 + o) * 3 + ky) * 3 + kx) * 2];
}

// ---------------------------------------------------------------------------
// conv_direct: 512 blocks (XCD-swizzled) = (b, 2-row group), 2 waves (128 thr).
//   Staging: wave w fills slabs {w, w+2} (image rows y0+rs-1): lane=x loads
//     8 channels per chunk (coalesced 256B/channel), cvt f16, swizzled
//     ds_write_b128. chunk = xp*8 + (ci^(xp&7)) -> conflict-free b128 ops.
//   Compute: wave w owns output row y0+w, full 64 outC: 4x4 16x16 frags.
//     K-loop = 3ky*3kx*2kc: 4 A ds_reads + 4 B global loads + 16 MFMA
//     (0.25 ds_read/MFMA -> below the MFMA-pipe floor).
//   C/D layout (m89/m91-verified): o = n*16 + (lane&15), x = m*16+(lane>>4)*4+j
// ---------------------------------------------------------------------------
__global__ __launch_bounds__(128, 2) void conv_direct(const float* __restrict__ imgs,
                                                      const _Float16* __restrict__ wf,
                                                      float* __restrict__ out) {
    __shared__ uint4 ldsb[4 * SLAB_BYTES / 16];   // 33,792 B
    char* lds = reinterpret_cast<char*>(ldsb);
    // XCD-aware swizzle (bijective: 512 = 8 * 64): XCD x gets b in {2x, 2x+1},
    // so each XCD's staged rows live in its own 4MB L2 (2 images = 2.1 MB).
    const int bid = blockIdx.x;
    const int swz = ((bid & 7) << 6) | (bid >> 3);
    const int b   = swz >> 5;
    const int y0  = (swz & 31) << 1;     // first output row of this block
    const int tid = threadIdx.x;
    const int w   = tid >> 6;            // wave 0..1
    const int l   = tid & 63;
    const int h   = l >> 4;              // k-chunk lane group
    const int r   = l & 15;              // A-row / B-col within fragment

    // ---- stage slabs rs = w, w+2 : image row y = y0 + rs - 1, 64 channels ----
    #pragma unroll
    for (int s = 0; s < 2; ++s) {
        const int rs = w + s * 2;
        const int y  = y0 + rs - 1;
        const bool yv = ((unsigned)y < (unsigned)NH);
        char* slab = lds + rs * SLAB_BYTES;
        #pragma unroll
        for (int ci = 0; ci < 8; ++ci) {
            f16x8 v;
            if (yv) {
                const float* src = imgs + (((size_t)(b * NC + ci * 8)) * NH + y) * NW + l;
                #pragma unroll
                for (int k = 0; k < 8; ++k) v[k] = (_Float16)src[(size_t)k * NH * NW];
            } else {
                #pragma unroll
                for (int k = 0; k < 8; ++k) v[k] = (_Float16)0.f;
            }
            const int xp = l + 1;                         // lane covers x = l
            const int chunk = xp * 8 + (ci ^ (xp & 7));
            *reinterpret_cast<f16x8*>(slab + chunk * 16) = v;
            if (l < 2) {                                  // pad columns xp = 0, 65
                const int xp2 = l ? 65 : 0;
                const int c2  = xp2 * 8 + (ci ^ (xp2 & 7));
                f16x8 z;
                #pragma unroll
                for (int k = 0; k < 8; ++k) z[k] = (_Float16)0.f;
                *reinterpret_cast<f16x8*>(slab + c2 * 16) = z;
            }
        }
    }
    __syncthreads();

    f32x4 acc[4][4];
    #pragma unroll
    for (int m = 0; m < 4; ++m)
        #pragma unroll
        for (int n = 0; n < 4; ++n)
            acc[m][n] = f32x4{0.f, 0.f, 0.f, 0.f};

    #pragma unroll
    for (int ky = 0; ky < 3; ++ky) {
        const char* slab = lds + (w + 2 - ky) * SLAB_BYTES;   // rs in 0..3
        #pragma unroll
        for (int kx = 0; kx < 3; ++kx) {
            const _Float16* wft = wf + (size_t)(ky * 3 + kx) * (2 * 4 * 64 * 8);
            #pragma unroll
            for (int kc = 0; kc < 2; ++kc) {
                f16x8 a[4], bb[4];
                #pragma unroll
                for (int m = 0; m < 4; ++m) {
                    const int xp = m * 16 + r + 2 - kx;          // 0..65
                    const int chunk = xp * 8 + (((kc << 2) + h) ^ (xp & 7));
                    a[m] = *reinterpret_cast<const f16x8*>(slab + chunk * 16);
                }
                #pragma unroll
                for (int n = 0; n < 4; ++n)
                    bb[n] = *reinterpret_cast<const f16x8*>(
                        wft + ((size_t)((kc << 2) + n) * 64 + l) * 8);
                #pragma unroll
                for (int m = 0; m < 4; ++m)
                    #pragma unroll
                    for (int n = 0; n < 4; ++n)
                        acc[m][n] = __builtin_amdgcn_mfma_f32_16x16x32_f16(a[m], bb[n], acc[m][n], 0, 0, 0);
            }
        }
    }

    const int y = y0 + w;
    #pragma unroll
    for (int m = 0; m < 4; ++m) {
        const int x0 = m * 16 + h * 4;
        #pragma unroll
        for (int n = 0; n < 4; ++n) {
            const int o = n * 16 + r;
            *reinterpret_cast<f32x4*>(out + (((size_t)(b * 64 + o) * 64 + y) * 64) + x0) = acc[m][n];
        }
    }
}

extern "C" void kernel_launch(void* const* d_in, const int* in_sizes, int n_in,
                              void* d_out, int out_size, void* d_ws, size_t ws_size,
                              hipStream_t stream) {
    const float* imgs  = (const float*)d_in[0];   // [16][64][64][64] f32
    const float* filts = (const float*)d_in[1];   // [1][64][64][3][3][2] f32
    float* out = (float*)d_out;                   // [16][64][64][64] f32
    _Float16* wfb = (_Float16*)d_ws;              // 73,728 B only

    hipLaunchKernelGGL(prep_w, dim3((WF_HALFS + 255) / 256), dim3(256), 0, stream, filts, wfb);
    hipLaunchKernelGGL(conv_direct, dim3(NB * 32), dim3(128), 0, stream, imgs, wfb, out);
}

// Round 6
// 22.497 us; speedup vs baseline: 1.2005x; 1.2005x over previous
//
#include <hip/hip_runtime.h>

// ---------------------------------------------------------------------------
// FFT_Conv_Layer == 3x3 "same" spatial conv with flipped REAL filter plane:
//   out[b,o,y,x] = sum_{i,ky,kx} filts[0,i,o,ky,kx,0] * img[b,i,y+1-ky,x+1-kx]
//
// R2 (22.5us): 512x256thr, wave 64x32, 2 blk/CU, 2 waves/SIMD, no swizzle.
// R3/R5 (27us, FAILED): wave 64x64 @128thr halved occupancy (grid caps blocks
//   at 2/CU; 1 wave/SIMD -> no latency hiding). Wave tile 64x32 is FORCED by
//   occupancy arithmetic: 131072 threads needed for 2 waves/SIMD over 4.19M
//   outputs -> 32 out/thread.
// R6: keep forced 64x32 wave tile, but 1024 blocks x 128 thr (1 output row
//   per block, 3 slabs, 25.3KB LDS) -> 4 blk/CU for cross-block overlap, plus
//   bijective XCD swizzle: each XCD owns 2 whole images (2.1MB < 4MB L2), so
//   all row-overlap re-reads are XCD-local L2 hits.
// ---------------------------------------------------------------------------

typedef _Float16 f16x8 __attribute__((ext_vector_type(8)));
typedef float    f32x4 __attribute__((ext_vector_type(4)));

#define NB 16
#define NC 64
#define NH 64
#define NW 64
#define CHUNKS 528                 // 66 xp positions * 8 channel-chunks per slab
#define SLAB_BYTES (CHUNKS * 16)   // 8448 B per image row slab
#define WF_HALFS (9 * 2 * 4 * 64 * 8)  // taps * kc * n * lane * elem = 36864

// ---------------------------------------------------------------------------
// prep_w: filts [1][inC][outC][3][3][2] f32 -> per-fragment f16 weights
//   Wf[t][kc][n][lane][e] = filts[0][ i=kc*32+(l/16)*8+e ][ o=n*16+l%16 ][ky][kx][0]
// ---------------------------------------------------------------------------
__global__ __launch_bounds__(256) void prep_w(const float* __restrict__ filts,
                                              _Float16* __restrict__ wf) {
    const int f = blockIdx.x * 256 + threadIdx.x;
    if (f >= WF_HALFS) return;
    const int e  = f & 7;
    const int l  = (f >> 3) & 63;
    const int n  = (f >> 9) & 3;
    const int kc = (f >> 11) & 1;
    const int t  = f >> 12;              // 0..8
    const int i  = kc * 32 + (l >> 4) * 8 + e;
    const int o  = n * 16 + (l & 15);
    const int ky = t / 3, kx = t % 3;
    wf[f] = (_Float16)filts[(((i * 64 + o) * 3 + ky) * 3 + kx) * 2];
}

// ---------------------------------------------------------------------------
// conv_row: 1024 blocks (XCD-swizzled) = (b, y), 2 waves (128 thr).
//   LDS: 3 slabs = image rows y-1, y, y+1 (yp = y-1+sl), swizzled chunks:
//     chunk = xp*8 + (ci^(xp&7)) -> conflict-free ds_write/ds_read_b128.
//   Staging: 24 (slab,chunk) groups round-robin over 2 waves; pads by tid<48.
//   Compute: wave w owns outC half w: 4m x 2n frags; K = 3ky*3kx*2kc,
//     per step 4 A ds_reads + 2 B global (L2) + 8 MFMA.
//   C/D layout (m89/m91-verified): o = n*16+(lane&15), x = m*16+(lane>>4)*4+j
// ---------------------------------------------------------------------------
__global__ __launch_bounds__(128, 2) void conv_row(const float* __restrict__ imgs,
                                                   const _Float16* __restrict__ wf,
                                                   float* __restrict__ out) {
    __shared__ uint4 ldsb[3 * SLAB_BYTES / 16];   // 25,344 B
    char* lds = reinterpret_cast<char*>(ldsb);
    // bijective XCD swizzle (1024 = 8*128): XCD x gets swz in [128x,128x+128)
    // = images {2x, 2x+1} -> all row re-reads are XCD-local L2 hits.
    const int bid = blockIdx.x;
    const int swz = ((bid & 7) << 7) | (bid >> 3);
    const int b   = swz >> 6;
    const int y   = swz & 63;            // output row
    const int tid = threadIdx.x;
    const int w   = tid >> 6;            // wave 0..1
    const int l   = tid & 63;
    const int h   = l >> 4;              // k-chunk lane group
    const int r   = l & 15;              // A-row / B-col within fragment

    // ---- pad columns xp = 0, 65 of all 3 slabs (48 zero b128 writes) ----
    if (tid < 48) {
        const int sl  = tid >> 4;
        const int rem = tid & 15;
        const int ci  = rem >> 1;
        const int xp2 = (rem & 1) ? 65 : 0;
        const int c2  = xp2 * 8 + (ci ^ (xp2 & 7));
        f16x8 z;
        #pragma unroll
        for (int k = 0; k < 8; ++k) z[k] = (_Float16)0.f;
        *reinterpret_cast<f16x8*>(lds + sl * SLAB_BYTES + c2 * 16) = z;
    }

    // ---- stage 3 slabs (rows y-1, y, y+1), 24 chunk-groups over 2 waves ----
    for (int g = w; g < 24; g += 2) {
        const int sl = g >> 3;           // slab 0..2
        const int ci = g & 7;            // channel chunk
        const int yy = y - 1 + sl;
        f16x8 v;
        if ((unsigned)yy < (unsigned)NH) {
            const float* src = imgs + (((size_t)(b * NC + ci * 8)) * NH + yy) * NW + l;
            #pragma unroll
            for (int k = 0; k < 8; ++k) v[k] = (_Float16)src[(size_t)k * NH * NW];
        } else {
            #pragma unroll
            for (int k = 0; k < 8; ++k) v[k] = (_Float16)0.f;
        }
        const int xp = l + 1;            // lane covers x = l
        const int chunk = xp * 8 + (ci ^ (xp & 7));
        *reinterpret_cast<f16x8*>(lds + sl * SLAB_BYTES + chunk * 16) = v;
    }
    __syncthreads();

    f32x4 acc[4][2];
    #pragma unroll
    for (int m = 0; m < 4; ++m)
        #pragma unroll
        for (int n = 0; n < 2; ++n)
            acc[m][n] = f32x4{0.f, 0.f, 0.f, 0.f};

    #pragma unroll
    for (int ky = 0; ky < 3; ++ky) {
        const char* slab = lds + (2 - ky) * SLAB_BYTES;   // img row y+1-ky
        #pragma unroll
        for (int kx = 0; kx < 3; ++kx) {
            const _Float16* wft = wf + (size_t)(ky * 3 + kx) * (2 * 4 * 64 * 8);
            #pragma unroll
            for (int kc = 0; kc < 2; ++kc) {
                f16x8 a[4], bb[2];
                #pragma unroll
                for (int m = 0; m < 4; ++m) {
                    const int xp = m * 16 + r + 2 - kx;          // 0..65
                    const int chunk = xp * 8 + (((kc << 2) + h) ^ (xp & 7));
                    a[m] = *reinterpret_cast<const f16x8*>(slab + chunk * 16);
                }
                #pragma unroll
                for (int n = 0; n < 2; ++n)
                    bb[n] = *reinterpret_cast<const f16x8*>(
                        wft + ((size_t)((kc << 2) + (w * 2 + n)) * 64 + l) * 8);
                #pragma unroll
                for (int m = 0; m < 4; ++m)
                    #pragma unroll
                    for (int n = 0; n < 2; ++n)
                        acc[m][n] = __builtin_amdgcn_mfma_f32_16x16x32_f16(a[m], bb[n], acc[m][n], 0, 0, 0);
            }
        }
    }

    #pragma unroll
    for (int m = 0; m < 4; ++m) {
        const int x0 = m * 16 + h * 4;
        #pragma unroll
        for (int n = 0; n < 2; ++n) {
            const int o = w * 32 + n * 16 + r;
            *reinterpret_cast<f32x4*>(out + (((size_t)(b * 64 + o) * 64 + y) * 64) + x0) = acc[m][n];
        }
    }
}

extern "C" void kernel_launch(void* const* d_in, const int* in_sizes, int n_in,
                              void* d_out, int out_size, void* d_ws, size_t ws_size,
                              hipStream_t stream) {
    const float* imgs  = (const float*)d_in[0];   // [16][64][64][64] f32
    const float* filts = (const float*)d_in[1];   // [1][64][64][3][3][2] f32
    float* out = (float*)d_out;                   // [16][64][64][64] f32
    _Float16* wfb = (_Float16*)d_ws;              // 73,728 B only

    hipLaunchKernelGGL(prep_w, dim3((WF_HALFS + 255) / 256), dim3(256), 0, stream, filts, wfb);
    hipLaunchKernelGGL(conv_row, dim3(NB * NH), dim3(128), 0, stream, imgs, wfb, out);
}

// Round 7
// 21.240 us; speedup vs baseline: 1.2716x; 1.0592x over previous
//
#include <hip/hip_runtime.h>

// ---------------------------------------------------------------------------
// FFT_Conv_Layer == 3x3 "same" spatial conv with flipped REAL filter plane:
//   out[b,o,y,x] = sum_{i,ky,kx} filts[0,i,o,ky,kx,0] * img[b,i,y+1-ky,x+1-kx]
//
// Ladder: R2 = 22.54us (512x256thr, 2-row blocks, wave 64x32, no swizzle)
//         R5 = 27.0us  (1 wave/SIMD — occupancy halved, +20%)
//         R6 = 22.50us (4blk/CU + swizzle + 1.5x staged traffic — net zero,
//                       CONFOUNDED: three levers moved at once)
// R7: single-lever A/B vs R2 — exact R2 structure + bijective XCD swizzle
//     only. XCD x owns images {2x,2x+1} (2.1MB f32 < 4MB L2) so the 2x row
//     re-read (16.8MB of 33.6MB staged) becomes XCD-local L2 hits.
//     If unchanged -> limiter is serial stage->barrier->compute latency;
//     next step is ky-interleaved staging.
// ---------------------------------------------------------------------------

typedef _Float16 f16x8 __attribute__((ext_vector_type(8)));
typedef float    f32x4 __attribute__((ext_vector_type(4)));

#define NB 16
#define NC 64
#define NH 64
#define NW 64
#define CHUNKS 528                 // 66 xp positions * 8 channel-chunks per slab
#define SLAB_BYTES (CHUNKS * 16)   // 8448 B per image row slab
#define WF_HALFS (9 * 2 * 4 * 64 * 8)  // taps * kc * n * lane * elem = 36864

// ---------------------------------------------------------------------------
// prep_w: filts [1][inC][outC][3][3][2] f32 -> per-fragment f16 weights
//   Wf[t][kc][n][lane][e] = filts[0][ i=kc*32+(l/16)*8+e ][ o=n*16+l%16 ][ky][kx][0]
// Same (lane-group,e)->k labeling as the A fragments, so the MFMA k-pairing
// is consistent regardless of the hardware's internal k bijection.
// ---------------------------------------------------------------------------
__global__ __launch_bounds__(256) void prep_w(const float* __restrict__ filts,
                                              _Float16* __restrict__ wf) {
    const int f = blockIdx.x * 256 + threadIdx.x;
    if (f >= WF_HALFS) return;
    const int e  = f & 7;
    const int l  = (f >> 3) & 63;
    const int n  = (f >> 9) & 3;
    const int kc = (f >> 11) & 1;
    const int t  = f >> 12;              // 0..8
    const int i  = kc * 32 + (l >> 4) * 8 + e;
    const int o  = n * 16 + (l & 15);
    const int ky = t / 3, kx = t % 3;
    wf[f] = (_Float16)filts[(((i * 64 + o) * 3 + ky) * 3 + kx) * 2];
}

// ---------------------------------------------------------------------------
// conv_direct: 512 blocks (XCD-swizzled) = (b, 2-row group), 4 waves (256 thr).
//   Staging: wave w fills LDS slab w (image row y0+w-1): lane=x loads
//     8 channels per chunk (coalesced 256B/channel), cvt f16, swizzled
//     ds_write_b128. chunk = xp*8 + (ci^(xp&7)) -> conflict-free b128 ops.
//   Compute: wave w owns (row = w>>1, outC half = w&1): 4x2 16x16 frags,
//     K-loop = 3ky*3kx*2kc: 4 A ds_reads + 2 B global loads + 8 MFMA.
//   C/D layout (m89/m91-verified): o = n*16+(lane&15), x = m*16+(lane>>4)*4+j
// ---------------------------------------------------------------------------
__global__ __launch_bounds__(256, 2) void conv_direct(const float* __restrict__ imgs,
                                                      const _Float16* __restrict__ wf,
                                                      float* __restrict__ out) {
    __shared__ uint4 ldsb[4 * SLAB_BYTES / 16];   // 33,792 B
    char* lds = reinterpret_cast<char*>(ldsb);
    // bijective XCD swizzle (512 = 8*64): XCD x gets swz in [64x, 64x+64)
    // = images {2x, 2x+1} -> staged row re-reads are XCD-local L2 hits.
    const int bid = blockIdx.x;
    const int swz = ((bid & 7) << 6) | (bid >> 3);
    const int b   = swz >> 5;
    const int y0  = (swz & 31) << 1;     // first output row of this block
    const int tid = threadIdx.x;
    const int w   = tid >> 6;            // wave 0..3
    const int l   = tid & 63;
    const int h   = l >> 4;              // k-chunk lane group
    const int r   = l & 15;              // A-row / B-col within fragment

    // ---- stage slab rs = w : image row y = y0 + rs - 1, all 64 channels ----
    {
        const int rs = w;
        const int y  = y0 + rs - 1;
        const bool yv = ((unsigned)y < (unsigned)NH);
        char* slab = lds + rs * SLAB_BYTES;
        #pragma unroll
        for (int ci = 0; ci < 8; ++ci) {
            f16x8 v;
            if (yv) {
                const float* src = imgs + (((size_t)(b * NC + ci * 8)) * NH + y) * NW + l;
                #pragma unroll
                for (int k = 0; k < 8; ++k) v[k] = (_Float16)src[(size_t)k * NH * NW];
            } else {
                #pragma unroll
                for (int k = 0; k < 8; ++k) v[k] = (_Float16)0.f;
            }
            const int xp = l + 1;                         // lane covers x = l
            const int chunk = xp * 8 + (ci ^ (xp & 7));
            *reinterpret_cast<f16x8*>(slab + chunk * 16) = v;
            if (l < 2) {                                  // pad columns xp = 0, 65
                const int xp2 = l ? 65 : 0;
                const int c2  = xp2 * 8 + (ci ^ (xp2 & 7));
                f16x8 z;
                #pragma unroll
                for (int k = 0; k < 8; ++k) z[k] = (_Float16)0.f;
                *reinterpret_cast<f16x8*>(slab + c2 * 16) = z;
            }
        }
    }
    __syncthreads();

    const int row = w >> 1;              // output row offset within group
    const int oh  = w & 1;               // outC half (0..1)

    f32x4 acc[4][2];
    #pragma unroll
    for (int m = 0; m < 4; ++m)
        #pragma unroll
        for (int n = 0; n < 2; ++n)
            acc[m][n] = f32x4{0.f, 0.f, 0.f, 0.f};

    #pragma unroll
    for (int ky = 0; ky < 3; ++ky) {
        const char* slab = lds + (row + 2 - ky) * SLAB_BYTES;   // rs in 0..3
        #pragma unroll
        for (int kx = 0; kx < 3; ++kx) {
            const _Float16* wft = wf + (size_t)(ky * 3 + kx) * (2 * 4 * 64 * 8);
            #pragma unroll
            for (int kc = 0; kc < 2; ++kc) {
                f16x8 a[4], bb[2];
                #pragma unroll
                for (int m = 0; m < 4; ++m) {
                    const int xp = m * 16 + r + 2 - kx;          // 0..65
                    const int chunk = xp * 8 + (((kc << 2) + h) ^ (xp & 7));
                    a[m] = *reinterpret_cast<const f16x8*>(slab + chunk * 16);
                }
                #pragma unroll
                for (int n = 0; n < 2; ++n)
                    bb[n] = *reinterpret_cast<const f16x8*>(
                        wft + ((size_t)((kc << 2) + (oh * 2 + n)) * 64 + l) * 8);
                #pragma unroll
                for (int m = 0; m < 4; ++m)
                    #pragma unroll
                    for (int n = 0; n < 2; ++n)
                        acc[m][n] = __builtin_amdgcn_mfma_f32_16x16x32_f16(a[m], bb[n], acc[m][n], 0, 0, 0);
            }
        }
    }

    const int y = y0 + row;
    #pragma unroll
    for (int m = 0; m < 4; ++m) {
        const int x0 = m * 16 + h * 4;
        #pragma unroll
        for (int n = 0; n < 2; ++n) {
            const int o = oh * 32 + n * 16 + r;
            *reinterpret_cast<f32x4*>(out + (((size_t)(b * 64 + o) * 64 + y) * 64) + x0) = acc[m][n];
        }
    }
}

extern "C" void kernel_launch(void* const* d_in, const int* in_sizes, int n_in,
                              void* d_out, int out_size, void* d_ws, size_t ws_size,
                              hipStream_t stream) {
    const float* imgs  = (const float*)d_in[0];   // [16][64][64][64] f32
    const float* filts = (const float*)d_in[1];   // [1][64][64][3][3][2] f32
    float* out = (float*)d_out;                   // [16][64][64][64] f32
    _Float16* wfb = (_Float16*)d_ws;              // 73,728 B only

    hipLaunchKernelGGL(prep_w, dim3((WF_HALFS + 255) / 256), dim3(256), 0, stream, filts, wfb);
    hipLaunchKernelGGL(conv_direct, dim3(NB * 32), dim3(256), 0, stream, imgs, wfb, out);
}

// Round 8
// 21.068 us; speedup vs baseline: 1.2819x; 1.0081x over previous
//
#include <hip/hip_runtime.h>

// ---------------------------------------------------------------------------
// FFT_Conv_Layer == 3x3 "same" spatial conv with flipped REAL filter plane:
//   out[b,o,y,x] = sum_{i,ky,kx} filts[0,i,o,ky,kx,0] * img[b,i,y+1-ky,x+1-kx]
//
// Ladder: R2 = 22.54us (512x256thr, wave 64x32, no swizzle)
//         R5 = 27.0us  (1 wave/SIMD: occupancy matters up to 2 waves/SIMD)
//         R6 = 22.50us (confounded 3-lever change, net zero)
//         R7 = 21.24us (R2 + bijective XCD swizzle: -1.3us, L2 locality real
//                       but minor). All throughput floors ~2-3us => kernel is
//                       latency-bound.
// R8: de-serialize staging (single lever). Old: per-chunk {8 loads -> cvt
//     (vmcnt(0)) -> ds_write} = 8 sequential HBM round-trips (~7200 cyc).
//     New: pass 1 issues all 64 loads into registers, pass 2 cvt+ds_write.
//     Pad writes hoisted to one branchless lane-mapped write.
// ---------------------------------------------------------------------------

typedef _Float16 f16x8 __attribute__((ext_vector_type(8)));
typedef float    f32x4 __attribute__((ext_vector_type(4)));

#define NB 16
#define NC 64
#define NH 64
#define NW 64
#define CHUNKS 528                 // 66 xp positions * 8 channel-chunks per slab
#define SLAB_BYTES (CHUNKS * 16)   // 8448 B per image row slab
#define WF_HALFS (9 * 2 * 4 * 64 * 8)  // taps * kc * n * lane * elem = 36864

// ---------------------------------------------------------------------------
// prep_w: filts [1][inC][outC][3][3][2] f32 -> per-fragment f16 weights
//   Wf[t][kc][n][lane][e] = filts[0][ i=kc*32+(l/16)*8+e ][ o=n*16+l%16 ][ky][kx][0]
// ---------------------------------------------------------------------------
__global__ __launch_bounds__(256) void prep_w(const float* __restrict__ filts,
                                              _Float16* __restrict__ wf) {
    const int f = blockIdx.x * 256 + threadIdx.x;
    if (f >= WF_HALFS) return;
    const int e  = f & 7;
    const int l  = (f >> 3) & 63;
    const int n  = (f >> 9) & 3;
    const int kc = (f >> 11) & 1;
    const int t  = f >> 12;              // 0..8
    const int i  = kc * 32 + (l >> 4) * 8 + e;
    const int o  = n * 16 + (l & 15);
    const int ky = t / 3, kx = t % 3;
    wf[f] = (_Float16)filts[(((i * 64 + o) * 3 + ky) * 3 + kx) * 2];
}

// ---------------------------------------------------------------------------
// conv_direct: 512 blocks (XCD-swizzled) = (b, 2-row group), 4 waves (256 thr).
//   Staging (R8): wave w stages slab w (image row y0+w-1). Pass 1: 64 scalar
//     f32 loads (all channels at x=lane) issued back-to-back into registers;
//     pass 2: cvt f16 + 8 swizzled ds_write_b128. Pads: lanes 0..15 write the
//     16 zero chunks (xp=0,65). chunk = xp*8 + (ci^(xp&7)) -> conflict-free.
//   Compute: wave w owns (row = w>>1, outC half = w&1): 4x2 16x16 frags,
//     K-loop = 3ky*3kx*2kc: 4 A ds_reads + 2 B global loads + 8 MFMA.
//   C/D layout (m89/m91-verified): o = n*16+(lane&15), x = m*16+(lane>>4)*4+j
// ---------------------------------------------------------------------------
__global__ __launch_bounds__(256, 2) void conv_direct(const float* __restrict__ imgs,
                                                      const _Float16* __restrict__ wf,
                                                      float* __restrict__ out) {
    __shared__ uint4 ldsb[4 * SLAB_BYTES / 16];   // 33,792 B
    char* lds = reinterpret_cast<char*>(ldsb);
    // bijective XCD swizzle (512 = 8*64): XCD x gets swz in [64x, 64x+64)
    // = images {2x, 2x+1} -> staged row re-reads are XCD-local L2 hits.
    const int bid = blockIdx.x;
    const int swz = ((bid & 7) << 6) | (bid >> 3);
    const int b   = swz >> 5;
    const int y0  = (swz & 31) << 1;     // first output row of this block
    const int tid = threadIdx.x;
    const int w   = tid >> 6;            // wave 0..3
    const int l   = tid & 63;
    const int h   = l >> 4;              // k-chunk lane group
    const int r   = l & 15;              // A-row / B-col within fragment

    // ---- stage slab rs = w : image row y = y0 + w - 1, all 64 channels ----
    {
        const int y  = y0 + w - 1;
        const bool yv = ((unsigned)y < (unsigned)NH);
        char* slab = lds + w * SLAB_BYTES;

        // pads: 16 zero chunks (xp = 0 and 65, 8 ci each), one lane each
        if (l < 16) {
            const int ci  = l >> 1;
            const int xp2 = (l & 1) ? 65 : 0;
            const int c2  = xp2 * 8 + (ci ^ (xp2 & 7));
            f16x8 z;
            #pragma unroll
            for (int k = 0; k < 8; ++k) z[k] = (_Float16)0.f;
            *reinterpret_cast<f16x8*>(slab + c2 * 16) = z;
        }

        // pass 1: issue all 64 loads (registers, static indices after unroll)
        float f[64];
        if (yv) {
            const float* src = imgs + (((size_t)(b * NC)) * NH + y) * NW + l;
            #pragma unroll
            for (int c = 0; c < 64; ++c)
                f[c] = src[(size_t)c * NH * NW];
        } else {
            #pragma unroll
            for (int c = 0; c < 64; ++c) f[c] = 0.f;
        }

        // pass 2: convert + swizzled ds_write_b128 per 8-channel chunk
        const int xp = l + 1;                          // lane covers x = l
        #pragma unroll
        for (int ci = 0; ci < 8; ++ci) {
            f16x8 v;
            #pragma unroll
            for (int k = 0; k < 8; ++k) v[k] = (_Float16)f[ci * 8 + k];
            const int chunk = xp * 8 + (ci ^ (xp & 7));
            *reinterpret_cast<f16x8*>(slab + chunk * 16) = v;
        }
    }
    __syncthreads();

    const int row = w >> 1;              // output row offset within group
    const int oh  = w & 1;               // outC half (0..1)

    f32x4 acc[4][2];
    #pragma unroll
    for (int m = 0; m < 4; ++m)
        #pragma unroll
        for (int n = 0; n < 2; ++n)
            acc[m][n] = f32x4{0.f, 0.f, 0.f, 0.f};

    #pragma unroll
    for (int ky = 0; ky < 3; ++ky) {
        const char* slab = lds + (row + 2 - ky) * SLAB_BYTES;   // rs in 0..3
        #pragma unroll
        for (int kx = 0; kx < 3; ++kx) {
            const _Float16* wft = wf + (size_t)(ky * 3 + kx) * (2 * 4 * 64 * 8);
            #pragma unroll
            for (int kc = 0; kc < 2; ++kc) {
                f16x8 a[4], bb[2];
                #pragma unroll
                for (int m = 0; m < 4; ++m) {
                    const int xp = m * 16 + r + 2 - kx;          // 0..65
                    const int chunk = xp * 8 + (((kc << 2) + h) ^ (xp & 7));
                    a[m] = *reinterpret_cast<const f16x8*>(slab + chunk * 16);
                }
                #pragma unroll
                for (int n = 0; n < 2; ++n)
                    bb[n] = *reinterpret_cast<const f16x8*>(
                        wft + ((size_t)((kc << 2) + (oh * 2 + n)) * 64 + l) * 8);
                #pragma unroll
                for (int m = 0; m < 4; ++m)
                    #pragma unroll
                    for (int n = 0; n < 2; ++n)
                        acc[m][n] = __builtin_amdgcn_mfma_f32_16x16x32_f16(a[m], bb[n], acc[m][n], 0, 0, 0);
            }
        }
    }

    const int y = y0 + row;
    #pragma unroll
    for (int m = 0; m < 4; ++m) {
        const int x0 = m * 16 + h * 4;
        #pragma unroll
        for (int n = 0; n < 2; ++n) {
            const int o = oh * 32 + n * 16 + r;
            *reinterpret_cast<f32x4*>(out + (((size_t)(b * 64 + o) * 64 + y) * 64) + x0) = acc[m][n];
        }
    }
}

extern "C" void kernel_launch(void* const* d_in, const int* in_sizes, int n_in,
                              void* d_out, int out_size, void* d_ws, size_t ws_size,
                              hipStream_t stream) {
    const float* imgs  = (const float*)d_in[0];   // [16][64][64][64] f32
    const float* filts = (const float*)d_in[1];   // [1][64][64][3][3][2] f32
    float* out = (float*)d_out;                   // [16][64][64][64] f32
    _Float16* wfb = (_Float16*)d_ws;              // 73,728 B only

    hipLaunchKernelGGL(prep_w, dim3((WF_HALFS + 255) / 256), dim3(256), 0, stream, filts, wfb);
    hipLaunchKernelGGL(conv_direct, dim3(NB * 32), dim3(256), 0, stream, imgs, wfb, out);
}